// Round 8
// baseline (130.449 us; speedup 1.0000x reference)
//
#include <hip/hip_runtime.h>
#include <math.h>

// KANConv2D via bf16 MFMA 16x16x32, R14.
// R14 = R13 GEMM + SINGLE-kernel fusion via software flag barrier.
// R8 lesson: hipLaunchCooperativeKernel silently no-ops under the harness.
// Here: plain launch; blocks 0..161 convert 1024 weight elems each (phase 0,
// = the whole 165888-elem cvt workload), phase 1 (x/bases, weight-independent)
// overlaps the stores' drain, then a per-block MAGIC flag in d_ws
// (release/acquire, agent scope, __threadfence) makes wst/wbt visible to all
// XCDs. Co-residency is structural (196 blocks <= 256 CUs -> no deadlock).
// Removes the cvt dispatch exec + inter-kernel gap (~5us attackable).
// Geometry (R10/R13, verified): 196 blocks (4 b x 7x7 tiles of 8x8 px, M=64),
// 512 thr = 8 waves, wave = (nq 0..3: oc quarter) x (kh 0..1: K half),
// 4 A-frags x 36 k32-steps per wave, double-buffered 9-slot B prefetch,
// cross-wave K-reduction via LDS SoA, kh=0 waves do the epilogue.
// Base conv k-order = tap*32 + c (tap-major) -> A from raw-x halo xh.
// Frag maps (validated R1/R6/R7/R10/R13 + m89/m120):
//   A: m = lane&15 (+16f), k = (lane>>4)*8 + j
//   B: n = lane&15, k = (lane>>4)*8 + j
//   C/D: col = lane&15 = n, row = (lane>>4)*4 + reg (+16f).

typedef __attribute__((ext_vector_type(8))) short bf16x8;
typedef __attribute__((ext_vector_type(4))) float f32x4;

#define MFMA16(a, b, c) __builtin_amdgcn_mfma_f32_16x16x32_bf16((a), (b), (c), 0, 0, 0)

#define NPROD 162          // producer blocks (162 * 1024 = 165888 cvt elems)
#define MAGIC 0x9E3779B1u  // no repeated-byte poison pattern can equal this

__device__ __forceinline__ unsigned short f2bf(float f) {
    unsigned u = __builtin_bit_cast(unsigned, f);
    u = (u + 0x7fffu + ((u >> 16) & 1u)) >> 16;   // RNE
    return (unsigned short)u;
}

__device__ __forceinline__ void eval_bases(float v, float bs[8]) {
    #pragma unroll
    for (int i = 0; i < 8; ++i) bs[i] = 0.0f;
    // knots: t_g = (g-3)*0.4 - 1, support [-2.2, 2.2)
    float t = (v + 2.2f) * 2.5f;
    if (t >= 0.0f && t < 11.0f) {
        int j = (int)t;
        if (j > 10) j = 10;
        float knot = (float)(j - 3) * 0.4f - 1.0f;
        float u  = (v - knot) * 2.5f;
        float um = 1.0f - u;
        float u2 = u * u, u3 = u2 * u;
        const float s6 = 1.0f / 6.0f;
        float w0 = um * um * um * s6;
        float w1 = (3.0f * u3 - 6.0f * u2 + 4.0f) * s6;
        float w2 = (-3.0f * u3 + 3.0f * u2 + 3.0f * u + 1.0f) * s6;
        float w3 = u3 * s6;
        int i0 = j - 3;
        if (i0 >= 0)               bs[i0]     = w0;
        if (i0 + 1 >= 0 && i0 < 7) bs[i0 + 1] = w1;
        if (i0 + 2 >= 0 && i0 < 6) bs[i0 + 2] = w2;
        if (i0 + 3 <= 7)           bs[i0 + 3] = w3;
    }
}

__global__ __launch_bounds__(512)
void kan_fused_kernel(const float* __restrict__ x,
                      const float* __restrict__ wb,
                      const float* __restrict__ ws,
                      const float* __restrict__ sc,
                      unsigned short* __restrict__ wst,
                      unsigned short* __restrict__ wbt,
                      unsigned* __restrict__ flags,
                      float* __restrict__ out) {
    // sb: bases [c 0..31][hp 0..99][8]   = 25600 us (51200 B)
    // xh: raw x [hp 0..99][40: 32 c+pad] =  4000 us ( 8000 B)  total 59200 B
    __shared__ unsigned short smem[29600];
    unsigned short* sb = smem;
    unsigned short* xh = smem + 25600;

    const int tid = threadIdx.x;
    const int bx  = blockIdx.x;              // 0..195
    const int b   = bx / 49;
    const int r   = bx - b * 49;
    const int ty  = r / 7;
    const int tx  = r - ty * 7;
    const int h0  = ty * 8, w0 = tx * 8;

    const int lane = tid & 63;
    const int wv   = tid >> 6;        // 0..7
    const int nq   = wv & 3;          // oc quarter (16 oc)
    const int kh   = wv >> 2;         // K half
    const int ml   = lane & 15;       // A row within frag / B,C col (oc)
    const int kg   = lane >> 4;       // k-group 0..3 within k32 step
    const int py0  = ml >> 3, px0 = ml & 7;   // frag-0 pixel (rows 0..15)

    // ---- phase 0: weight cvt+swizzle slice (2 elems/thread, blocks < NPROD) ----
    // wst (spline, k = p*8+basis): wst[((q*72+S)*64+l)*8+j] = ws[(q*16+(l&15))*2304 + S*32 + (l>>4)*8 + j]
    // wbt (base, tap-major):       wbt[((q*9+s)*64+l)*8+j]  = wb[(q*16+(l&15))*288 + ((l>>4)*8+j)*9 + s]
    if (bx < NPROD) {
        #pragma unroll
        for (int e = 0; e < 2; ++e) {
            int gid = bx * 1024 + e * 512 + tid;    // 0..165887
            if (gid < 147456) {
                int j = gid & 7, l = (gid >> 3) & 63, t = gid >> 9;   // t 0..287
                int S = t % 72, q = t / 72;
                int oc = q * 16 + (l & 15);
                int k  = S * 32 + (l >> 4) * 8 + j;
                wst[gid] = f2bf(ws[oc * 2304 + k]);
            } else {
                int i2 = gid - 147456;               // < 18432
                int j = i2 & 7, l = (i2 >> 3) & 63, t = i2 >> 9;      // t 0..35
                int s = t % 9, q = t / 9;
                int oc = q * 16 + (l & 15);
                int c  = (l >> 4) * 8 + j;
                wbt[i2] = f2bf(wb[oc * 288 + c * 9 + s]);
            }
        }
    }

    // ---- phase 1: 3200 halo elems (10x10x32), batched loads, 1 store each ----
    float vv[7];
    #pragma unroll
    for (int j = 0; j < 7; ++j) {
        int i = tid + j * 512;        // 0..3583
        float val = 0.0f;
        if (i < 3200) {
            int c  = i / 100;
            int hp = i - c * 100;
            int hy = hp / 10;
            int hx = hp - hy * 10;
            int hh = h0 + hy - 1, ww = w0 + hx - 1;
            if ((unsigned)hh < 56u && (unsigned)ww < 56u)
                val = x[((b * 32 + c) * 56 + hh) * 56 + ww];
        }
        vv[j] = val;
    }
    #pragma unroll
    for (int j = 0; j < 7; ++j) {
        int i = tid + j * 512;
        if (i < 3200) {
            int c  = i / 100;
            int hp = i - c * 100;
            float bs[8];
            eval_bases(vv[j], bs);
            bf16x8 pk;
            #pragma unroll
            for (int j2 = 0; j2 < 8; ++j2) pk[j2] = (short)f2bf(bs[j2]);
            *reinterpret_cast<bf16x8*>(&sb[i * 8]) = pk;   // i = c*100+hp
            xh[hp * 40 + c] = f2bf(vv[j]);
        }
    }

    // ---- software grid barrier: publish cvt slices, wait for all NPROD ----
    __threadfence();                  // drain this thread's wst/wbt stores (device scope)
    __syncthreads();                  // all block threads' stores now fenced
    if (bx < NPROD && tid == 0)
        __hip_atomic_store(&flags[bx], MAGIC, __ATOMIC_RELEASE, __HIP_MEMORY_SCOPE_AGENT);
    if (tid < NPROD) {
        while (__hip_atomic_load(&flags[tid], __ATOMIC_ACQUIRE, __HIP_MEMORY_SCOPE_AGENT) != MAGIC)
            __builtin_amdgcn_s_sleep(1);
    }
    __syncthreads();                  // everyone saw all flags; sb/xh also ready
    __threadfence();                  // acquire: no stale wst/wbt lines below

    // ---- B prefetch (bf16 streams, now valid) ----
    const unsigned short* bp = wst + ((nq * 72 + kh * 36) * 64 + lane) * 8;
    bf16x8 bwbuf[2][9];
    #pragma unroll
    for (int u = 0; u < 9; ++u)
        bwbuf[0][u] = *reinterpret_cast<const bf16x8*>(bp + u * 512);

    const int sbeg = kh ? 5 : 0;
    const int nST  = kh ? 4 : 5;
    bf16x8 bbv[5];
    {
        const unsigned short* bbp = wbt + (nq * 9 * 64 + lane) * 8;
        #pragma unroll
        for (int s = 0; s < 5; ++s)
            if (s < nST)
                bbv[s] = *reinterpret_cast<const bf16x8*>(bbp + (sbeg + s) * 512);
    }

    // spline A offsets (ushort units): step S reads p = 4S + kg
    //   -> dc = (4u+kg)/9 within the g-quad, tap = (4u+kg)%9.
    // frag f = +2 tile rows = +f*160 ushorts.
    int aoff[9];
    #pragma unroll
    for (int u = 0; u < 9; ++u) {
        int tt  = 4 * u + kg;         // 0..35
        int dc  = tt / 9;
        int tap = tt - dc * 9;
        int th  = tap / 3;
        int tw  = tap - th * 3;
        aoff[u] = (dc * 100 + (py0 + th) * 10 + (px0 + tw)) * 8;
    }

    f32x4 aS[4] = {{0,0,0,0},{0,0,0,0},{0,0,0,0},{0,0,0,0}};
    f32x4 aB[4] = {{0,0,0,0},{0,0,0,0},{0,0,0,0},{0,0,0,0}};

    // ---- spline GEMM: 36 k32-steps, double-buffered 9-slot B prefetch ----
    // g fully unrolled -> bwbuf indices static (regs, no scratch).
    #pragma unroll
    for (int g = 0; g < 4; ++g) {
        const int cur = g & 1;
        if (g < 3) {
            #pragma unroll
            for (int u = 0; u < 9; ++u)
                bwbuf[cur ^ 1][u] =
                    *reinterpret_cast<const bf16x8*>(bp + ((g + 1) * 9 + u) * 512);
        }
        const int cbase = kh * 12800 + g * 3200;   // channel-quad base (us)
        #pragma unroll
        for (int u = 0; u < 9; ++u) {
            #pragma unroll
            for (int f = 0; f < 4; ++f) {
                bf16x8 a = *reinterpret_cast<const bf16x8*>(&sb[cbase + aoff[u] + f * 160]);
                aS[f] = MFMA16(a, bwbuf[cur][u], aS[f]);
            }
        }
    }

    // ---- base GEMM (tap-major): kh=0 -> taps 0..4, kh=1 -> taps 5..8 ----
    #pragma unroll
    for (int s = 0; s < 5; ++s)
        if (s < nST) {
            const int tap = sbeg + s;
            const int th  = tap >= 6 ? 2 : (tap >= 3 ? 1 : 0);
            const int tw  = tap - 3 * th;
            const int xa  = ((py0 + th) * 10 + (px0 + tw)) * 40 + kg * 8;
            #pragma unroll
            for (int f = 0; f < 4; ++f) {          // frag f = +2 rows = +800 us
                bf16x8 a = *reinterpret_cast<const bf16x8*>(&xh[xa + f * 800]);
                aB[f] = MFMA16(a, bbv[s], aB[f]);
            }
        }

    // ---- cross-wave K reduction via LDS (SoA: [32 words][260], conflict-free) ----
    __syncthreads();                               // all sb/xh reads done
    float* red = reinterpret_cast<float*>(smem);   // 32*260*4 = 33280 B
    const int idx = nq * 64 + lane;                // 0..255, same for the kh pair
    if (kh) {
        #pragma unroll
        for (int f = 0; f < 4; ++f) {
            #pragma unroll
            for (int w = 0; w < 4; ++w) red[(f * 4 + w) * 260 + idx] = aS[f][w];
        }
        #pragma unroll
        for (int f = 0; f < 4; ++f) {
            #pragma unroll
            for (int w = 0; w < 4; ++w) red[((16 + f * 4) + w) * 260 + idx] = aB[f][w];
        }
    }
    __syncthreads();
    if (!kh) {
        #pragma unroll
        for (int f = 0; f < 4; ++f) {
            #pragma unroll
            for (int w = 0; w < 4; ++w) aS[f][w] += red[(f * 4 + w) * 260 + idx];
        }
        #pragma unroll
        for (int f = 0; f < 4; ++f) {
            #pragma unroll
            for (int w = 0; w < 4; ++w) aB[f][w] += red[((16 + f * 4) + w) * 260 + idx];
        }

        // ---- epilogue: row m = f*16 + kg*4 + reg -> py = f*2+(kg>>1), px = (kg&1)*4+reg
        const int oc  = nq * 16 + ml;
        const float scv = sc[oc];
        #pragma unroll
        for (int f = 0; f < 4; ++f) {
            const int py  = f * 2 + (kg >> 1);
            const int pxb = (kg & 1) * 4;
            float* ob = out + ((b * 64 + oc) * 56 + h0 + py) * 56 + w0 + pxb;
            f32x4 res;
            #pragma unroll
            for (int reg = 0; reg < 4; ++reg) {
                float bv = aB[f][reg];
                float si = bv / (1.0f + __expf(-bv));
                res[reg] = si + scv * aS[f][reg];
            }
            *reinterpret_cast<f32x4*>(ob) = res;
        }
    }
}

extern "C" void kernel_launch(void* const* d_in, const int* in_sizes, int n_in,
                              void* d_out, int out_size, void* d_ws, size_t ws_size,
                              hipStream_t stream) {
    const float* x  = (const float*)d_in[0];   // (4,32,56,56)
    const float* wb = (const float*)d_in[1];   // (64,32,3,3)
    const float* ws = (const float*)d_in[2];   // (64,288,8)
    const float* sc = (const float*)d_in[3];   // (64,)
    float* out = (float*)d_out;                // (4,64,56,56)

    unsigned short* wst = (unsigned short*)d_ws;       // 147456 bf16
    unsigned short* wbt = wst + 147456;                // 18432 bf16
    unsigned* flags = (unsigned*)((char*)d_ws + 331776);  // NPROD flags (poisoned each iter)

    kan_fused_kernel<<<196, 512, 0, stream>>>(x, wb, ws, sc, wst, wbt, flags, out);
}

// Round 9
// 78.241 us; speedup vs baseline: 1.6673x; 1.6673x over previous
//
#include <hip/hip_runtime.h>
#include <math.h>

// KANConv2D via bf16 MFMA, R15.
// R15 = R10's balanced skeleton + 32x32x16 MFMA (R11's A-traffic win without
// R11's imbalance). Wave cube: (nqq 0..1: 32-oc half) x (kh 0..1: K half) x
// (mh 0..1: 32-row M half) — every wave identical: 72 spline K16-steps +
// 9 base K16-steps, one 32x32 A-frag. Spline A-LDS: 1.15MB -> 576KB/block.
// Reduction = R10's proven 2-way SoA ([32 words][260], kh pairs), epilogue
// on the 4 kh=0 waves. B double-buffered 9-slot register prefetch (R13).
// R14 lesson: software flag barriers cost ~60us (cross-XCD spin) — two-kernel
// structure (cvt + main) is the right skeleton; d_ws poison fill is fixed
// harness overhead either way (R9).
// - Main: 196 blocks (4 b x 7x7 tiles of 8x8 px, M=64), 512 thr = 8 waves.
// - Base conv k-order = tap*32 + c (tap-major) -> A from raw-x halo xh.
// Frag maps (32x32x16, validated by R11 passing + m74/m101):
//   A: m = lane&31 (+32mh), k = (lane>>5)*8 + j
//   B: n = lane&31, k = (lane>>5)*8 + j
//   C/D: col = lane&31 = n, row = (reg&3) + 8*(reg>>2) + 4*(lane>>5) (+32mh)

typedef __attribute__((ext_vector_type(8))) short bf16x8;
typedef __attribute__((ext_vector_type(4))) float f32x4;
typedef __attribute__((ext_vector_type(16))) float f32x16;

#define MFMA32(a, b, c) __builtin_amdgcn_mfma_f32_32x32x16_bf16((a), (b), (c), 0, 0, 0)

__device__ __forceinline__ unsigned short f2bf(float f) {
    unsigned u = __builtin_bit_cast(unsigned, f);
    u = (u + 0x7fffu + ((u >> 16) & 1u)) >> 16;   // RNE
    return (unsigned short)u;
}

__device__ __forceinline__ void eval_bases(float v, float bs[8]) {
    #pragma unroll
    for (int i = 0; i < 8; ++i) bs[i] = 0.0f;
    // knots: t_g = (g-3)*0.4 - 1, support [-2.2, 2.2)
    float t = (v + 2.2f) * 2.5f;
    if (t >= 0.0f && t < 11.0f) {
        int j = (int)t;
        if (j > 10) j = 10;
        float knot = (float)(j - 3) * 0.4f - 1.0f;
        float u  = (v - knot) * 2.5f;
        float um = 1.0f - u;
        float u2 = u * u, u3 = u2 * u;
        const float s6 = 1.0f / 6.0f;
        float w0 = um * um * um * s6;
        float w1 = (3.0f * u3 - 6.0f * u2 + 4.0f) * s6;
        float w2 = (-3.0f * u3 + 3.0f * u2 + 3.0f * u + 1.0f) * s6;
        float w3 = u3 * s6;
        int i0 = j - 3;
        if (i0 >= 0)               bs[i0]     = w0;
        if (i0 + 1 >= 0 && i0 < 7) bs[i0 + 1] = w1;
        if (i0 + 2 >= 0 && i0 < 6) bs[i0 + 2] = w2;
        if (i0 + 3 <= 7)           bs[i0 + 3] = w3;
    }
}

// ---- pre-kernel: fp32 weights -> bf16 32-col B-frag streams (R11, verified) ----
// wst[((nqq*144+t)*64+l)*8+j] = ws[(nqq*32+(l&31))*2304 + t*16 + (l>>5)*8 + j]
// wbt[((nqq*18 +t)*64+l)*8+j] = wb[(nqq*32+(l&31))*288 + c*9 + tap],
//   where tap = t>>1, c = 16*(t&1) + (l>>5)*8 + j   (k-order = tap*32 + c)
__global__ __launch_bounds__(256)
void cvt_swz_kernel(const float* __restrict__ ws, const float* __restrict__ wb,
                    unsigned short* __restrict__ wst, unsigned short* __restrict__ wbt) {
    int i = blockIdx.x * 256 + threadIdx.x;
    if (i < 147456) {
        int j = i & 7, l = (i >> 3) & 63, tq = i >> 9;   // tq 0..287
        int t = tq % 144, nqq = tq / 144;
        int oc = nqq * 32 + (l & 31);
        int k  = t * 16 + (l >> 5) * 8 + j;
        wst[i] = f2bf(ws[oc * 2304 + k]);
    } else {
        int i2 = i - 147456;
        if (i2 < 18432) {
            int j = i2 & 7, l = (i2 >> 3) & 63, tq = i2 >> 9;  // tq 0..35
            int t = tq % 18, nqq = tq / 18;
            int oc  = nqq * 32 + (l & 31);
            int tap = t >> 1;
            int c   = 16 * (t & 1) + (l >> 5) * 8 + j;
            wbt[i2] = f2bf(wb[oc * 288 + c * 9 + tap]);
        }
    }
}

__global__ __launch_bounds__(512)
void kan_mfma_kernel(const float* __restrict__ x,
                     const float* __restrict__ sc,
                     const unsigned short* __restrict__ wst,
                     const unsigned short* __restrict__ wbt,
                     float* __restrict__ out) {
    // sb: bases [c 0..31][hp 0..99][8]   = 25600 us (51200 B)
    // xh: raw x [hp 0..99][40: 32 c+pad] =  4000 us ( 8000 B)  total 59200 B
    __shared__ unsigned short smem[29600];
    unsigned short* sb = smem;
    unsigned short* xh = smem + 25600;

    const int tid = threadIdx.x;
    const int bx  = blockIdx.x;              // 0..195
    const int b   = bx / 49;
    const int r   = bx - b * 49;
    const int ty  = r / 7;
    const int tx  = r - ty * 7;
    const int h0  = ty * 8, w0 = tx * 8;

    const int lane = tid & 63;
    const int wv   = tid >> 6;        // 0..7
    const int nqq  = wv & 1;          // oc half (32 oc)
    const int kh   = (wv >> 1) & 1;   // K half
    const int mh   = wv >> 2;         // M half (32 rows)
    const int rl   = lane & 31;       // A row within frag / B,C col
    const int hl   = lane >> 5;       // k-subgroup 0..1 within K16 step
    const int py0  = (rl >> 3) + 4 * mh;      // pixel row of A row
    const int px0  = rl & 7;                  // pixel col

    // ---- phase 1: 3200 halo elems (10x10x32), batched loads, 1 store each ----
    float vv[7];
    #pragma unroll
    for (int j = 0; j < 7; ++j) {
        int i = tid + j * 512;        // 0..3583
        float val = 0.0f;
        if (i < 3200) {
            int c  = i / 100;
            int hp = i - c * 100;
            int hy = hp / 10;
            int hx = hp - hy * 10;
            int hh = h0 + hy - 1, ww = w0 + hx - 1;
            if ((unsigned)hh < 56u && (unsigned)ww < 56u)
                val = x[((b * 32 + c) * 56 + hh) * 56 + ww];
        }
        vv[j] = val;
    }
    #pragma unroll
    for (int j = 0; j < 7; ++j) {
        int i = tid + j * 512;
        if (i < 3200) {
            int c  = i / 100;
            int hp = i - c * 100;
            float bs[8];
            eval_bases(vv[j], bs);
            bf16x8 pk;
            #pragma unroll
            for (int j2 = 0; j2 < 8; ++j2) pk[j2] = (short)f2bf(bs[j2]);
            *reinterpret_cast<bf16x8*>(&sb[i * 8]) = pk;   // i = c*100+hp
            xh[hp * 40 + c] = f2bf(vv[j]);
        }
    }

    // ---- B prefetch (issued before the barrier; stream valid: cvt ran first) ----
    const unsigned short* bp = wst + ((nqq * 144 + kh * 72) * 64 + lane) * 8;
    bf16x8 bwbuf[2][9];
    #pragma unroll
    for (int u = 0; u < 9; ++u)
        bwbuf[0][u] = *reinterpret_cast<const bf16x8*>(bp + u * 512);

    bf16x8 bbv[9];
    {
        const unsigned short* bbp = wbt + ((nqq * 18 + kh * 9) * 64 + lane) * 8;
        #pragma unroll
        for (int s = 0; s < 9; ++s)
            bbv[s] = *reinterpret_cast<const bf16x8*>(bbp + s * 512);
    }

    __syncthreads();

    // spline A offsets (ushort units): step t reads patch-pos p = 2t + hl.
    // Within a 9-step group: tt = 2u + hl (0..17): dc = tt/9, tap = tt%9.
    int aoff[9];
    #pragma unroll
    for (int u = 0; u < 9; ++u) {
        int tt  = 2 * u + hl;         // 0..17
        int dc  = tt >= 9 ? 1 : 0;
        int tap = tt - 9 * dc;
        int th  = tap / 3;
        int tw  = tap - th * 3;
        aoff[u] = (dc * 100 + (py0 + th) * 10 + (px0 + tw)) * 8;
    }

    f32x16 accS = {0,0,0,0,0,0,0,0,0,0,0,0,0,0,0,0};
    f32x16 accB = {0,0,0,0,0,0,0,0,0,0,0,0,0,0,0,0};

    // ---- spline GEMM: 72 K16-steps (t = kh*72 + a*9 + u), 8 groups of 9 ----
    // group a covers channels (kh*16 + 2a) + dc; double-buffered B prefetch.
    #pragma unroll
    for (int a = 0; a < 8; ++a) {
        const int cur = a & 1;
        if (a < 7) {
            #pragma unroll
            for (int u = 0; u < 9; ++u)
                bwbuf[cur ^ 1][u] =
                    *reinterpret_cast<const bf16x8*>(bp + ((a + 1) * 9 + u) * 512);
        }
        const int cbase = (kh * 16 + 2 * a) * 800;   // channel * 100 hp * 8
        #pragma unroll
        for (int u = 0; u < 9; ++u) {
            bf16x8 av = *reinterpret_cast<const bf16x8*>(&sb[cbase + aoff[u]]);
            accS = MFMA32(av, bwbuf[cur][u], accS);
        }
    }

    // ---- base GEMM (tap-major): 9 K16-steps, t = kh*9 + s ----
    #pragma unroll
    for (int s = 0; s < 9; ++s) {
        const int t   = kh * 9 + s;                // wave-uniform
        const int tap = t >> 1;
        const int th  = tap >= 6 ? 2 : (tap >= 3 ? 1 : 0);
        const int tw  = tap - 3 * th;
        const int xa  = ((py0 + th) * 10 + (px0 + tw)) * 40 + 16 * (t & 1) + hl * 8;
        bf16x8 av = *reinterpret_cast<const bf16x8*>(&xh[xa]);
        accB = MFMA32(av, bbv[s], accB);
    }

    // ---- cross-wave K reduction via LDS (SoA: [32 words][260], conflict-free) ----
    __syncthreads();                               // all sb/xh reads done
    float* red = reinterpret_cast<float*>(smem);   // 32*260*4 = 33280 B
    const int idx = (mh * 2 + nqq) * 64 + lane;    // 0..255, same for the kh pair
    if (kh) {
        #pragma unroll
        for (int w = 0; w < 16; ++w) red[w * 260 + idx] = accS[w];
        #pragma unroll
        for (int w = 0; w < 16; ++w) red[(16 + w) * 260 + idx] = accB[w];
    }
    __syncthreads();
    if (!kh) {
        #pragma unroll
        for (int w = 0; w < 16; ++w) accS[w] += red[w * 260 + idx];
        #pragma unroll
        for (int w = 0; w < 16; ++w) accB[w] += red[(16 + w) * 260 + idx];

        // ---- epilogue: row = (reg&3) + 8*(reg>>2) + 4*hl + 32*mh ----
        //   -> py = mh*4 + (reg>>2), px = 4*hl + (reg&3): f32x4 per reg-quad.
        const int oc  = nqq * 32 + rl;
        const float scv = sc[oc];
        #pragma unroll
        for (int q = 0; q < 4; ++q) {
            float* ob = out + ((b * 64 + oc) * 56 + h0 + mh * 4 + q) * 56 + w0 + 4 * hl;
            f32x4 res;
            #pragma unroll
            for (int rr = 0; rr < 4; ++rr) {
                float bv = accB[q * 4 + rr];
                float si = bv / (1.0f + __expf(-bv));
                res[rr] = si + scv * accS[q * 4 + rr];
            }
            *reinterpret_cast<f32x4*>(ob) = res;
        }
    }
}

extern "C" void kernel_launch(void* const* d_in, const int* in_sizes, int n_in,
                              void* d_out, int out_size, void* d_ws, size_t ws_size,
                              hipStream_t stream) {
    const float* x  = (const float*)d_in[0];   // (4,32,56,56)
    const float* wb = (const float*)d_in[1];   // (64,32,3,3)
    const float* ws = (const float*)d_in[2];   // (64,288,8)
    const float* sc = (const float*)d_in[3];   // (64,)
    float* out = (float*)d_out;                // (4,64,56,56)

    unsigned short* wst = (unsigned short*)d_ws;   // 147456 bf16
    unsigned short* wbt = wst + 147456;            // 18432 bf16

    cvt_swz_kernel<<<648, 256, 0, stream>>>(ws, wb, wst, wbt);
    kan_mfma_kernel<<<196, 512, 0, stream>>>(x, sc, wst, wbt, out);
}

// Round 10
// 76.906 us; speedup vs baseline: 1.6962x; 1.0174x over previous
//
#include <hip/hip_runtime.h>
#include <math.h>

// KANConv2D via bf16 MFMA 16x16x32, R16.
// R16 = R10 skeleton with per-step MFMA shape {2 A-frags x 2 B-frags -> 4 MFMA}
// instead of {4 A x 1 B}: wave = (nqq: 32-oc half) x (kh: K half) x (mh:
// 32-row M half). Same MFMA count, same 4 independent 36-deep acc chains
// (R15 lesson: one f32x16 acc serializes the K-chain — 32x32 MFMA loses),
// but spline A-LDS traffic halves (1.15MB -> 576KB/block; LDS is the
// dominant main-kernel pipe per R14's 1.19M bank-conflict profile).
// B L2 bytes double (registers, latency hidden — R13 proved neutral).
// - cvt kernel (R10/R13, verified): fp32 weights -> bf16 16-col B-frag
//   streams in d_ws (poison fill is fixed harness overhead — R9 proved).
// - Main: 196 blocks (4 b x 7x7 tiles of 8x8 px, M=64), 512 thr = 8 waves;
//   cross-wave kh-pair K-reduction via LDS SoA; kh=0 waves do the epilogue.
// - Base conv k-order = tap*32 + c (tap-major) -> A from raw-x halo xh.
// Frag maps (validated R1/R6/R7/R10/R13 + m89/m120):
//   A: m = lane&15 (+16*mi +32*mh), k = (lane>>4)*8 + j
//   B: n = lane&15 (+16*ni +32*nqq), k = (lane>>4)*8 + j
//   C/D: col = lane&15 = n, row = (lane>>4)*4 + reg (+16*mi +32*mh).

typedef __attribute__((ext_vector_type(8))) short bf16x8;
typedef __attribute__((ext_vector_type(4))) float f32x4;

#define MFMA16(a, b, c) __builtin_amdgcn_mfma_f32_16x16x32_bf16((a), (b), (c), 0, 0, 0)

__device__ __forceinline__ unsigned short f2bf(float f) {
    unsigned u = __builtin_bit_cast(unsigned, f);
    u = (u + 0x7fffu + ((u >> 16) & 1u)) >> 16;   // RNE
    return (unsigned short)u;
}

__device__ __forceinline__ void eval_bases(float v, float bs[8]) {
    #pragma unroll
    for (int i = 0; i < 8; ++i) bs[i] = 0.0f;
    // knots: t_g = (g-3)*0.4 - 1, support [-2.2, 2.2)
    float t = (v + 2.2f) * 2.5f;
    if (t >= 0.0f && t < 11.0f) {
        int j = (int)t;
        if (j > 10) j = 10;
        float knot = (float)(j - 3) * 0.4f - 1.0f;
        float u  = (v - knot) * 2.5f;
        float um = 1.0f - u;
        float u2 = u * u, u3 = u2 * u;
        const float s6 = 1.0f / 6.0f;
        float w0 = um * um * um * s6;
        float w1 = (3.0f * u3 - 6.0f * u2 + 4.0f) * s6;
        float w2 = (-3.0f * u3 + 3.0f * u2 + 3.0f * u + 1.0f) * s6;
        float w3 = u3 * s6;
        int i0 = j - 3;
        if (i0 >= 0)               bs[i0]     = w0;
        if (i0 + 1 >= 0 && i0 < 7) bs[i0 + 1] = w1;
        if (i0 + 2 >= 0 && i0 < 6) bs[i0 + 2] = w2;
        if (i0 + 3 <= 7)           bs[i0 + 3] = w3;
    }
}

// ---- pre-kernel: fp32 weights -> bf16 B-frag streams (R10/R13, verified) ----
// wst (spline, k = p*8 + basis):
//   wst[((nq*72+S)*64+l)*8+j] = ws[(nq*16+(l&15))*2304 + S*32 + (l>>4)*8 + j]
// wbt (base, tap-major k = tap*32 + c):
//   wbt[((nq*9+s)*64+l)*8+j]  = wb[(nq*16+(l&15))*288 + ((l>>4)*8+j)*9 + s]
__global__ __launch_bounds__(256)
void cvt_swz_kernel(const float* __restrict__ ws, const float* __restrict__ wb,
                    unsigned short* __restrict__ wst, unsigned short* __restrict__ wbt) {
    int i = blockIdx.x * 256 + threadIdx.x;
    if (i < 147456) {
        int j = i & 7, l = (i >> 3) & 63, t = i >> 9;   // t 0..287
        int S = t % 72, nq = t / 72;
        int oc = nq * 16 + (l & 15);
        int k  = S * 32 + (l >> 4) * 8 + j;
        wst[i] = f2bf(ws[oc * 2304 + k]);
    } else {
        int i2 = i - 147456;
        if (i2 < 18432) {
            int j = i2 & 7, l = (i2 >> 3) & 63, t = i2 >> 9;  // t 0..35
            int s = t % 9, nq = t / 9;
            int oc = nq * 16 + (l & 15);
            int c  = (l >> 4) * 8 + j;
            wbt[i2] = f2bf(wb[oc * 288 + c * 9 + s]);
        }
    }
}

__global__ __launch_bounds__(512)
void kan_mfma_kernel(const float* __restrict__ x,
                     const float* __restrict__ sc,
                     const unsigned short* __restrict__ wst,
                     const unsigned short* __restrict__ wbt,
                     float* __restrict__ out) {
    // sb: bases [c 0..31][hp 0..99][8]   = 25600 us (51200 B)
    // xh: raw x [hp 0..99][40: 32 c+pad] =  4000 us ( 8000 B)  total 59200 B
    __shared__ unsigned short smem[29600];
    unsigned short* sb = smem;
    unsigned short* xh = smem + 25600;

    const int tid = threadIdx.x;
    const int bx  = blockIdx.x;              // 0..195
    const int b   = bx / 49;
    const int r   = bx - b * 49;
    const int ty  = r / 7;
    const int tx  = r - ty * 7;
    const int h0  = ty * 8, w0 = tx * 8;

    const int lane = tid & 63;
    const int wv   = tid >> 6;        // 0..7
    const int nqq  = wv & 1;          // oc half (32 oc: quarters 2nqq, 2nqq+1)
    const int kh   = (wv >> 1) & 1;   // K half
    const int mh   = wv >> 2;         // M half (32 rows)
    const int ml   = lane & 15;       // A row within frag / B,C col within frag
    const int kg   = lane >> 4;       // k-group 0..3 within k32 step
    const int py0  = mh * 4 + (ml >> 3);      // pixel row of A row (mi=0)
    const int px0  = ml & 7;                  // pixel col

    // ---- phase 1: 3200 halo elems (10x10x32), batched loads, 1 store each ----
    float vv[7];
    #pragma unroll
    for (int j = 0; j < 7; ++j) {
        int i = tid + j * 512;        // 0..3583
        float val = 0.0f;
        if (i < 3200) {
            int c  = i / 100;
            int hp = i - c * 100;
            int hy = hp / 10;
            int hx = hp - hy * 10;
            int hh = h0 + hy - 1, ww = w0 + hx - 1;
            if ((unsigned)hh < 56u && (unsigned)ww < 56u)
                val = x[((b * 32 + c) * 56 + hh) * 56 + ww];
        }
        vv[j] = val;
    }
    #pragma unroll
    for (int j = 0; j < 7; ++j) {
        int i = tid + j * 512;
        if (i < 3200) {
            int c  = i / 100;
            int hp = i - c * 100;
            float bs[8];
            eval_bases(vv[j], bs);
            bf16x8 pk;
            #pragma unroll
            for (int j2 = 0; j2 < 8; ++j2) pk[j2] = (short)f2bf(bs[j2]);
            *reinterpret_cast<bf16x8*>(&sb[i * 8]) = pk;   // i = c*100+hp
            xh[hp * 40 + c] = f2bf(vv[j]);
        }
    }
    __syncthreads();

    // spline A offsets (ushort units): step S reads p = 4S + kg
    //   -> dc = (4u+kg)/9 within the g-quad, tap = (4u+kg)%9.
    // mi frag (rows +16) = +2 tile rows = +160 ushorts; mh folded into py0.
    int aoff[9];
    #pragma unroll
    for (int u = 0; u < 9; ++u) {
        int tt  = 4 * u + kg;         // 0..35
        int dc  = tt / 9;
        int tap = tt - dc * 9;
        int th  = tap / 3;
        int tw  = tap - th * 3;
        aoff[u] = (dc * 100 + (py0 + th) * 10 + (px0 + tw)) * 8;
    }

    f32x4 aS[2][2] = {{{0,0,0,0},{0,0,0,0}},{{0,0,0,0},{0,0,0,0}}};
    f32x4 aB[2][2] = {{{0,0,0,0},{0,0,0,0}},{{0,0,0,0},{0,0,0,0}}};

    // ---- spline GEMM: 36 k32-steps (S = kh*36 + g*9 + u), 2A x 2B per step ----
    const unsigned short* bp0 = wst + ((nqq * 2 * 72 + kh * 36) * 64 + lane) * 8;
    const unsigned short* bp1 = bp0 + 36864;       // next oc quarter (+72*512)
    for (int g = 0; g < 4; ++g) {
        const int cbase = kh * 12800 + g * 3200;   // channel-quad base (us)
        #pragma unroll
        for (int u = 0; u < 9; ++u) {
            const int so = (g * 9 + u) * 512;
            bf16x8 bw0 = *reinterpret_cast<const bf16x8*>(bp0 + so);
            bf16x8 bw1 = *reinterpret_cast<const bf16x8*>(bp1 + so);
            bf16x8 a0  = *reinterpret_cast<const bf16x8*>(&sb[cbase + aoff[u]]);
            bf16x8 a1  = *reinterpret_cast<const bf16x8*>(&sb[cbase + aoff[u] + 160]);
            aS[0][0] = MFMA16(a0, bw0, aS[0][0]);
            aS[0][1] = MFMA16(a0, bw1, aS[0][1]);
            aS[1][0] = MFMA16(a1, bw0, aS[1][0]);
            aS[1][1] = MFMA16(a1, bw1, aS[1][1]);
        }
    }

    // ---- base GEMM (tap-major): kh=0 -> taps 0..4, kh=1 -> taps 5..8 ----
    {
        const unsigned short* bbp0 = wbt + (nqq * 2 * 9 * 64 + lane) * 8;
        const unsigned short* bbp1 = bbp0 + 4608;  // next oc quarter (+9*512)
        const int sbeg = kh ? 5 : 0;
        const int nST  = kh ? 4 : 5;
        #pragma unroll
        for (int s = 0; s < 5; ++s)
            if (s < nST) {
                const int tap = sbeg + s;
                const int th  = tap >= 6 ? 2 : (tap >= 3 ? 1 : 0);
                const int tw  = tap - 3 * th;
                const int so  = tap * 512;
                const int xa  = ((py0 + th) * 10 + (px0 + tw)) * 40 + kg * 8;
                bf16x8 bw0 = *reinterpret_cast<const bf16x8*>(bbp0 + so);
                bf16x8 bw1 = *reinterpret_cast<const bf16x8*>(bbp1 + so);
                bf16x8 a0  = *reinterpret_cast<const bf16x8*>(&xh[xa]);
                bf16x8 a1  = *reinterpret_cast<const bf16x8*>(&xh[xa + 800]);
                aB[0][0] = MFMA16(a0, bw0, aB[0][0]);
                aB[0][1] = MFMA16(a0, bw1, aB[0][1]);
                aB[1][0] = MFMA16(a1, bw0, aB[1][0]);
                aB[1][1] = MFMA16(a1, bw1, aB[1][1]);
            }
    }

    // ---- cross-wave kh-pair reduction via LDS (SoA [32 words][260]) ----
    __syncthreads();                               // all sb/xh reads done
    float* red = reinterpret_cast<float*>(smem);   // 32*260*4 = 33280 B
    const int idx = (mh * 2 + nqq) * 64 + lane;    // 0..255, same for the kh pair
    if (kh) {
        #pragma unroll
        for (int mi = 0; mi < 2; ++mi)
            #pragma unroll
            for (int ni = 0; ni < 2; ++ni)
                #pragma unroll
                for (int w = 0; w < 4; ++w)
                    red[((mi * 2 + ni) * 4 + w) * 260 + idx] = aS[mi][ni][w];
        #pragma unroll
        for (int mi = 0; mi < 2; ++mi)
            #pragma unroll
            for (int ni = 0; ni < 2; ++ni)
                #pragma unroll
                for (int w = 0; w < 4; ++w)
                    red[(16 + (mi * 2 + ni) * 4 + w) * 260 + idx] = aB[mi][ni][w];
    }
    __syncthreads();
    if (!kh) {
        #pragma unroll
        for (int mi = 0; mi < 2; ++mi)
            #pragma unroll
            for (int ni = 0; ni < 2; ++ni)
                #pragma unroll
                for (int w = 0; w < 4; ++w)
                    aS[mi][ni][w] += red[((mi * 2 + ni) * 4 + w) * 260 + idx];
        #pragma unroll
        for (int mi = 0; mi < 2; ++mi)
            #pragma unroll
            for (int ni = 0; ni < 2; ++ni)
                #pragma unroll
                for (int w = 0; w < 4; ++w)
                    aB[mi][ni][w] += red[(16 + (mi * 2 + ni) * 4 + w) * 260 + idx];

        // ---- epilogue: m = mh*32 + mi*16 + kg*4 + reg ----
        //   -> py = mh*4 + mi*2 + (kg>>1), px = (kg&1)*4 + reg.
        #pragma unroll
        for (int ni = 0; ni < 2; ++ni) {
            const int oc  = nqq * 32 + ni * 16 + ml;
            const float scv = sc[oc];
            #pragma unroll
            for (int mi = 0; mi < 2; ++mi) {
                const int py  = mh * 4 + mi * 2 + (kg >> 1);
                const int pxb = (kg & 1) * 4;
                float* ob = out + ((b * 64 + oc) * 56 + h0 + py) * 56 + w0 + pxb;
                f32x4 res;
                #pragma unroll
                for (int reg = 0; reg < 4; ++reg) {
                    float bv = aB[mi][ni][reg];
                    float si = bv / (1.0f + __expf(-bv));
                    res[reg] = si + scv * aS[mi][ni][reg];
                }
                *reinterpret_cast<f32x4*>(ob) = res;
            }
        }
    }
}

extern "C" void kernel_launch(void* const* d_in, const int* in_sizes, int n_in,
                              void* d_out, int out_size, void* d_ws, size_t ws_size,
                              hipStream_t stream) {
    const float* x  = (const float*)d_in[0];   // (4,32,56,56)
    const float* wb = (const float*)d_in[1];   // (64,32,3,3)
    const float* ws = (const float*)d_in[2];   // (64,288,8)
    const float* sc = (const float*)d_in[3];   // (64,)
    float* out = (float*)d_out;                // (4,64,56,56)

    unsigned short* wst = (unsigned short*)d_ws;   // 147456 bf16
    unsigned short* wbt = wst + 147456;            // 18432 bf16

    cvt_swz_kernel<<<648, 256, 0, stream>>>(ws, wb, wst, wbt);
    kan_mfma_kernel<<<196, 512, 0, stream>>>(x, sc, wst, wbt, out);
}

// Round 11
// 74.740 us; speedup vs baseline: 1.7454x; 1.0290x over previous
//
#include <hip/hip_runtime.h>
#include <math.h>

// KANConv2D via bf16 MFMA 16x16x32, R17 = exact revert to R10 (best: 73.17us).
// Ablation summary (R11/R15/R16 all regressed): A-LDS traffic is NOT the
// critical path; R10's {1 B-frag x 4 A-frags -> 4 MFMA} shape maximizes issue
// density per B-register. Fusion attempts (R8 coop / R9,R12 in-reg cvt / R14
// flag barrier) all lost: two-kernel cvt+main is the right skeleton.
// R10: M=64 tiles, scatter-free phase 1 via tap-major base-weight K-reorder,
// 196 blocks (one per CU).
// - cvt kernel pre-swizzles fp32 weights -> bf16 MFMA B-frag streams in d_ws
//   (d_ws poison fill is fixed harness overhead regardless of use — R9 proved).
// - Main: 196 blocks (4 b x 7x7 tiles of 8x8 px, M=64), 512 thr = 8 waves:
//   wave = (nq 0..3: oc quarter of 16) x (kh 0..1: K half). Each wave: 4
//   A-frags (16 rows each) x 36 k32-steps, 8 f32x4 accs; cross-wave K
//   reduction via LDS SoA; kh=0 waves do the epilogue.
// - Base conv uses k-order k = tap*32 + c (tap-major): A-frag j-dim = 8
//   consecutive CHANNELS at one spatial pos -> read raw-x halo xh[hp][c]
//   directly, no im2col scatter. Spline k-order unchanged (p*8 + basis).
// Frag maps (validated by passing R1/R6/R7 kernels / m89/m120):
//   A: m = lane&15 (+16f for frag f), k = (lane>>4)*8 + j
//   B: n = lane&15, k = (lane>>4)*8 + j
//   C/D: col = lane&15 = n, row = (lane>>4)*4 + reg (+16f for frag f).

typedef __attribute__((ext_vector_type(8))) short bf16x8;
typedef __attribute__((ext_vector_type(4))) float f32x4;

#define MFMA16(a, b, c) __builtin_amdgcn_mfma_f32_16x16x32_bf16((a), (b), (c), 0, 0, 0)

__device__ __forceinline__ unsigned short f2bf(float f) {
    unsigned u = __builtin_bit_cast(unsigned, f);
    u = (u + 0x7fffu + ((u >> 16) & 1u)) >> 16;   // RNE
    return (unsigned short)u;
}

__device__ __forceinline__ void eval_bases(float v, float bs[8]) {
    #pragma unroll
    for (int i = 0; i < 8; ++i) bs[i] = 0.0f;
    // knots: t_g = (g-3)*0.4 - 1, support [-2.2, 2.2)
    float t = (v + 2.2f) * 2.5f;
    if (t >= 0.0f && t < 11.0f) {
        int j = (int)t;
        if (j > 10) j = 10;
        float knot = (float)(j - 3) * 0.4f - 1.0f;
        float u  = (v - knot) * 2.5f;
        float um = 1.0f - u;
        float u2 = u * u, u3 = u2 * u;
        const float s6 = 1.0f / 6.0f;
        float w0 = um * um * um * s6;
        float w1 = (3.0f * u3 - 6.0f * u2 + 4.0f) * s6;
        float w2 = (-3.0f * u3 + 3.0f * u2 + 3.0f * u + 1.0f) * s6;
        float w3 = u3 * s6;
        int i0 = j - 3;
        if (i0 >= 0)               bs[i0]     = w0;
        if (i0 + 1 >= 0 && i0 < 7) bs[i0 + 1] = w1;
        if (i0 + 2 >= 0 && i0 < 6) bs[i0 + 2] = w2;
        if (i0 + 3 <= 7)           bs[i0 + 3] = w3;
    }
}

// ---- pre-kernel: fp32 weights -> bf16 B-frag streams ----
// wst (spline, k = p*8 + basis, unchanged):
//   wst[((nq*72+S)*64+l)*8+j] = ws[(nq*16+(l&15))*2304 + S*32 + (l>>4)*8 + j]
// wbt (base, tap-major k = tap*32 + c):
//   wbt[((nq*9+s)*64+l)*8+j]  = wb[(nq*16+(l&15))*288 + ((l>>4)*8+j)*9 + s]
__global__ __launch_bounds__(256)
void cvt_swz_kernel(const float* __restrict__ ws, const float* __restrict__ wb,
                    unsigned short* __restrict__ wst, unsigned short* __restrict__ wbt) {
    int i = blockIdx.x * 256 + threadIdx.x;
    if (i < 147456) {
        int j = i & 7, l = (i >> 3) & 63, t = i >> 9;   // t 0..287
        int S = t % 72, nq = t / 72;
        int oc = nq * 16 + (l & 15);
        int k  = S * 32 + (l >> 4) * 8 + j;
        wst[i] = f2bf(ws[oc * 2304 + k]);
    } else {
        int i2 = i - 147456;
        if (i2 < 18432) {
            int j = i2 & 7, l = (i2 >> 3) & 63, t = i2 >> 9;  // t 0..35
            int s = t % 9, nq = t / 9;
            int oc = nq * 16 + (l & 15);
            int c  = (l >> 4) * 8 + j;
            wbt[i2] = f2bf(wb[oc * 288 + c * 9 + s]);
        }
    }
}

__global__ __launch_bounds__(512)
void kan_mfma_kernel(const float* __restrict__ x,
                     const float* __restrict__ sc,
                     const unsigned short* __restrict__ wst,
                     const unsigned short* __restrict__ wbt,
                     float* __restrict__ out) {
    // sb: bases [c 0..31][hp 0..99][8]   = 25600 us (51200 B)
    // xh: raw x [hp 0..99][40: 32 c+pad] =  4000 us ( 8000 B)  total 59200 B
    __shared__ unsigned short smem[29600];
    unsigned short* sb = smem;
    unsigned short* xh = smem + 25600;

    const int tid = threadIdx.x;
    const int bx  = blockIdx.x;              // 0..195
    const int b   = bx / 49;
    const int r   = bx - b * 49;
    const int ty  = r / 7;
    const int tx  = r - ty * 7;
    const int h0  = ty * 8, w0 = tx * 8;

    const int lane = tid & 63;
    const int wv   = tid >> 6;        // 0..7
    const int nq   = wv & 3;          // oc quarter (16 oc)
    const int kh   = wv >> 2;         // K half
    const int ml   = lane & 15;       // A row within frag / B,C col (oc)
    const int kg   = lane >> 4;       // k-group 0..3 within k32 step
    const int py0  = ml >> 3, px0 = ml & 7;   // frag-0 pixel (rows 0..15)

    // ---- phase 1: 3200 halo elems (10x10x32), batched loads, 1 store each ----
    float vv[7];
    #pragma unroll
    for (int j = 0; j < 7; ++j) {
        int i = tid + j * 512;        // 0..3583
        float val = 0.0f;
        if (i < 3200) {
            int c  = i / 100;
            int hp = i - c * 100;
            int hy = hp / 10;
            int hx = hp - hy * 10;
            int hh = h0 + hy - 1, ww = w0 + hx - 1;
            if ((unsigned)hh < 56u && (unsigned)ww < 56u)
                val = x[((b * 32 + c) * 56 + hh) * 56 + ww];
        }
        vv[j] = val;
    }
    #pragma unroll
    for (int j = 0; j < 7; ++j) {
        int i = tid + j * 512;
        if (i < 3200) {
            int c  = i / 100;
            int hp = i - c * 100;
            float bs[8];
            eval_bases(vv[j], bs);
            bf16x8 pk;
            #pragma unroll
            for (int j2 = 0; j2 < 8; ++j2) pk[j2] = (short)f2bf(bs[j2]);
            *reinterpret_cast<bf16x8*>(&sb[i * 8]) = pk;   // i = c*100+hp
            xh[hp * 40 + c] = f2bf(vv[j]);
        }
    }
    __syncthreads();

    // spline A offsets (ushort units): step S = 9g+u reads p = 4S + kg
    //   -> c = 4g + (4u+kg)/9, tap = (4u+kg)%9.  aoff is g-independent.
    int aoff[9];
    #pragma unroll
    for (int u = 0; u < 9; ++u) {
        int tt  = 4 * u + kg;         // 0..35
        int dc  = tt / 9;
        int tap = tt - dc * 9;
        int th  = tap / 3;
        int tw  = tap - th * 3;
        aoff[u] = (dc * 100 + (py0 + th) * 10 + (px0 + tw)) * 8;
    }

    f32x4 aS[4] = {{0,0,0,0},{0,0,0,0},{0,0,0,0},{0,0,0,0}};
    f32x4 aB[4] = {{0,0,0,0},{0,0,0,0},{0,0,0,0},{0,0,0,0}};

    // ---- spline GEMM: this wave's 36 k32-steps (S = kh*36 + g*9 + u) ----
    const unsigned short* bp = wst + ((nq * 72 + kh * 36) * 64 + lane) * 8;
    for (int g = 0; g < 4; ++g) {
        const int cbase = kh * 12800 + g * 3200;   // channel-quad base (us)
        #pragma unroll
        for (int u = 0; u < 9; ++u) {
            bf16x8 bw = *reinterpret_cast<const bf16x8*>(bp + (g * 9 + u) * 512);
            #pragma unroll
            for (int f = 0; f < 4; ++f) {
                bf16x8 a = *reinterpret_cast<const bf16x8*>(&sb[cbase + aoff[u] + f * 160]);
                aS[f] = MFMA16(a, bw, aS[f]);
            }
        }
    }

    // ---- base GEMM (tap-major): steps s: kh=0 -> 0..4, kh=1 -> 5..8 ----
    {
        const unsigned short* bbp = wbt + (nq * 9 * 64 + lane) * 8;
        const int sbeg = kh ? 5 : 0;
        const int send = kh ? 9 : 5;
        for (int s = sbeg; s < send; ++s) {
            int th = (s * 11) >> 5;           // s/3 for s in 0..8
            int tw = s - 3 * th;
            bf16x8 bw = *reinterpret_cast<const bf16x8*>(bbp + s * 512);
            int xa = ((py0 + th) * 10 + (px0 + tw)) * 40 + kg * 8;
            #pragma unroll
            for (int f = 0; f < 4; ++f) {     // frag f = +2 rows = +800 us
                bf16x8 a = *reinterpret_cast<const bf16x8*>(&xh[xa + f * 800]);
                aB[f] = MFMA16(a, bw, aB[f]);
            }
        }
    }

    // ---- cross-wave K reduction via LDS (SoA: [32 words][260], conflict-free) ----
    __syncthreads();                               // all sb/xh reads done
    float* red = reinterpret_cast<float*>(smem);   // 32*260*4 = 33280 B
    const int idx = nq * 64 + lane;                // 0..255, same for the kh pair
    if (kh) {
        #pragma unroll
        for (int f = 0; f < 4; ++f) {
            #pragma unroll
            for (int w = 0; w < 4; ++w) red[(f * 4 + w) * 260 + idx] = aS[f][w];
        }
        #pragma unroll
        for (int f = 0; f < 4; ++f) {
            #pragma unroll
            for (int w = 0; w < 4; ++w) red[((16 + f * 4) + w) * 260 + idx] = aB[f][w];
        }
    }
    __syncthreads();
    if (!kh) {
        #pragma unroll
        for (int f = 0; f < 4; ++f) {
            #pragma unroll
            for (int w = 0; w < 4; ++w) aS[f][w] += red[(f * 4 + w) * 260 + idx];
        }
        #pragma unroll
        for (int f = 0; f < 4; ++f) {
            #pragma unroll
            for (int w = 0; w < 4; ++w) aB[f][w] += red[((16 + f * 4) + w) * 260 + idx];
        }

        // ---- epilogue: row m = f*16 + kg*4 + reg -> py = f*2+(kg>>1), px = (kg&1)*4+reg
        const int oc  = nq * 16 + ml;
        const float scv = sc[oc];
        #pragma unroll
        for (int f = 0; f < 4; ++f) {
            const int py  = f * 2 + (kg >> 1);
            const int pxb = (kg & 1) * 4;
            float* ob = out + ((b * 64 + oc) * 56 + h0 + py) * 56 + w0 + pxb;
            f32x4 res;
            #pragma unroll
            for (int reg = 0; reg < 4; ++reg) {
                float bv = aB[f][reg];
                float si = bv / (1.0f + __expf(-bv));
                res[reg] = si + scv * aS[f][reg];
            }
            *reinterpret_cast<f32x4*>(ob) = res;
        }
    }
}

extern "C" void kernel_launch(void* const* d_in, const int* in_sizes, int n_in,
                              void* d_out, int out_size, void* d_ws, size_t ws_size,
                              hipStream_t stream) {
    const float* x  = (const float*)d_in[0];   // (4,32,56,56)
    const float* wb = (const float*)d_in[1];   // (64,32,3,3)
    const float* ws = (const float*)d_in[2];   // (64,288,8)
    const float* sc = (const float*)d_in[3];   // (64,)
    float* out = (float*)d_out;                // (4,64,56,56)

    unsigned short* wst = (unsigned short*)d_ws;   // 147456 bf16
    unsigned short* wbt = wst + 147456;            // 18432 bf16

    cvt_swz_kernel<<<648, 256, 0, stream>>>(ws, wb, wst, wbt);
    kan_mfma_kernel<<<196, 512, 0, stream>>>(x, sc, wst, wbt, out);
}